// Round 1
// 13408.185 us; speedup vs baseline: 1.6114x; 1.6114x over previous
//
#include <hip/hip_runtime.h>
#include <stdint.h>

// ---------------- threefry2x32 (bit-exact vs JAX) ----------------
__device__ __forceinline__ uint32_t rotl32(uint32_t v, int r) {
    return (v << r) | (v >> (32 - r));
}

__device__ __forceinline__ void threefry2x32(uint32_t k0, uint32_t k1,
                                             uint32_t x0, uint32_t x1,
                                             uint32_t& o0, uint32_t& o1) {
    const uint32_t k2 = k0 ^ k1 ^ 0x1BD11BDAu;
    x0 += k0; x1 += k1;
#define TF_RND(r) { x0 += x1; x1 = rotl32(x1, r); x1 ^= x0; }
    TF_RND(13) TF_RND(15) TF_RND(26) TF_RND(6)
    x0 += k1; x1 += k2 + 1u;
    TF_RND(17) TF_RND(29) TF_RND(16) TF_RND(24)
    x0 += k2; x1 += k0 + 2u;
    TF_RND(13) TF_RND(15) TF_RND(26) TF_RND(6)
    x0 += k0; x1 += k1 + 3u;
    TF_RND(17) TF_RND(29) TF_RND(16) TF_RND(24)
    x0 += k1; x1 += k2 + 4u;
    TF_RND(13) TF_RND(15) TF_RND(26) TF_RND(6)
    x0 += k2; x1 += k0 + 5u;
#undef TF_RND
    o0 = x0; o1 = x1;
}

// ---------------- MFMA bf16 hi/lo split-precision GEMM ----------------
// C[M,N] = A[M,K] @ B[N,K]^T + bias, fp32 in/out, ~fp32 accuracy via
// 3-product bf16 split: a*b ~= ah*bh + al*bh + ah*bl  (error ~2^-18 rel).
// Block: 256 threads = 4 waves; block tile 64x64, each wave 32x32 (2x2 frags
// of mfma_f32_16x16x32_bf16). BK=64, LDS planes XOR-swizzled for b128 reads.

typedef __attribute__((ext_vector_type(8))) __bf16 bf16x8;
typedef __attribute__((ext_vector_type(4))) __bf16 bf16x4;
typedef __attribute__((ext_vector_type(4))) float f32x4;

constexpr int TM = 64, TN = 64, TK = 64;

// stage one 64x64 fp32 tile -> hi/lo bf16 LDS planes (swizzled)
__device__ __forceinline__ void stage_tile(
    __bf16* __restrict__ Hs, __bf16* __restrict__ Ls,
    const float* __restrict__ P, long long ld, int r0, int k0, int tid)
{
#pragma unroll
    for (int i = 0; i < 4; ++i) {
        const int flat = i * 256 + tid;
        const int row  = flat >> 4;          // 0..63
        const int k4   = (flat & 15) << 2;   // 0,4,..,60
        const float4 v = *(const float4*)(P + (long long)(r0 + row) * ld + (k0 + k4));
        const __bf16 h0 = (__bf16)v.x, h1 = (__bf16)v.y, h2 = (__bf16)v.z, h3 = (__bf16)v.w;
        const __bf16 l0 = (__bf16)(v.x - (float)h0);
        const __bf16 l1 = (__bf16)(v.y - (float)h1);
        const __bf16 l2 = (__bf16)(v.z - (float)h2);
        const __bf16 l3 = (__bf16)(v.w - (float)h3);
        const int e = (row * TK + k4) ^ ((row & 7) << 3);   // element-domain swizzle
        *(bf16x4*)&Hs[e] = (bf16x4){h0, h1, h2, h3};
        *(bf16x4*)&Ls[e] = (bf16x4){l0, l1, l2, l3};
    }
}

template<bool ATOMIC>
__device__ __forceinline__ void mfma_gemm_body(
    __bf16* Ah_s, __bf16* Al_s, __bf16* Bh_s, __bf16* Bl_s,
    const float* __restrict__ A, long long lda,
    const float* __restrict__ B, long long ldb,
    const float* __restrict__ bias,
    float* __restrict__ C, int ldc,
    int m0, int n0, int kbase, int ksize)
{
    const int tid  = threadIdx.x;
    const int lane = tid & 63;
    const int wid  = tid >> 6;
    const int wr   = (wid >> 1) << 5;   // 0 or 32 (m)
    const int wc   = (wid & 1) << 5;    // 0 or 32 (n)
    const int fr   = lane & 15;
    const int kg   = lane >> 4;         // 0..3

    f32x4 acc[2][2] = {};

    for (int k0 = kbase; k0 < kbase + ksize; k0 += TK) {
        stage_tile(Ah_s, Al_s, A, lda, m0, k0, tid);
        stage_tile(Bh_s, Bl_s, B, ldb, n0, k0, tid);
        __syncthreads();
#pragma unroll
        for (int kc = 0; kc < 2; ++kc) {
            const int kb = kc * 32 + kg * 8;
            bf16x8 ah[2], al[2], bh[2], bl[2];
#pragma unroll
            for (int i = 0; i < 2; ++i) {
                const int r  = wr + i * 16 + fr;
                const int ea = (r * TK + kb) ^ ((r & 7) << 3);
                ah[i] = *(const bf16x8*)&Ah_s[ea];
                al[i] = *(const bf16x8*)&Al_s[ea];
                const int c  = wc + i * 16 + fr;
                const int eb = (c * TK + kb) ^ ((c & 7) << 3);
                bh[i] = *(const bf16x8*)&Bh_s[eb];
                bl[i] = *(const bf16x8*)&Bl_s[eb];
            }
#pragma unroll
            for (int i = 0; i < 2; ++i)
#pragma unroll
                for (int j = 0; j < 2; ++j)
                    acc[i][j] = __builtin_amdgcn_mfma_f32_16x16x32_bf16(ah[i], bh[j], acc[i][j], 0, 0, 0);
#pragma unroll
            for (int i = 0; i < 2; ++i)
#pragma unroll
                for (int j = 0; j < 2; ++j)
                    acc[i][j] = __builtin_amdgcn_mfma_f32_16x16x32_bf16(al[i], bh[j], acc[i][j], 0, 0, 0);
#pragma unroll
            for (int i = 0; i < 2; ++i)
#pragma unroll
                for (int j = 0; j < 2; ++j)
                    acc[i][j] = __builtin_amdgcn_mfma_f32_16x16x32_bf16(ah[i], bl[j], acc[i][j], 0, 0, 0);
        }
        __syncthreads();
    }

    // C/D layout (m89-verified): col = lane&15, row = (lane>>4)*4 + reg
#pragma unroll
    for (int i = 0; i < 2; ++i)
#pragma unroll
        for (int j = 0; j < 2; ++j)
#pragma unroll
            for (int v = 0; v < 4; ++v) {
                const int row = m0 + wr + i * 16 + kg * 4 + v;
                const int col = n0 + wc + j * 16 + fr;
                float val = acc[i][j][v];
                if (ATOMIC) {
                    atomicAdd(&C[(long long)row * ldc + col], val);
                } else {
                    if (bias) val += bias[col];
                    C[(long long)row * ldc + col] = val;
                }
            }
}

__global__ __launch_bounds__(256) void k_gemm_abT(
    const float* __restrict__ A, long long lda,
    const float* __restrict__ B, long long ldb,
    const float* __restrict__ bias,
    float* __restrict__ C, int ldc, int K)
{
    __shared__ __bf16 sm[4][TM * TK];
    mfma_gemm_body<false>(sm[0], sm[1], sm[2], sm[3], A, lda, B, ldb, bias, C, ldc,
                          blockIdx.y * TM, blockIdx.x * TN, 0, K);
}

// gi = x @ W_ih^T + b_ih (K=256) ; gh = h @ W_hh^T + b_hh (K=1024)
__global__ __launch_bounds__(256) void k_gru_gemms(
    const float* __restrict__ x, const float* __restrict__ h,
    const float* __restrict__ W_ih, const float* __restrict__ W_hh,
    const float* __restrict__ b_ih, const float* __restrict__ b_hh,
    float* __restrict__ gi, float* __restrict__ gh)
{
    __shared__ __bf16 sm[4][TM * TK];
    if (blockIdx.z == 0)
        mfma_gemm_body<false>(sm[0], sm[1], sm[2], sm[3], x, 256, W_ih, 256, b_ih, gi, 3072,
                              blockIdx.y * TM, blockIdx.x * TN, 0, 256);
    else
        mfma_gemm_body<false>(sm[0], sm[1], sm[2], sm[3], h, 1024, W_hh, 1024, b_hh, gh, 3072,
                              blockIdx.y * TM, blockIdx.x * TN, 0, 1024);
}

// x += Y @ E  via pre-transposed Et[N=256,K=8192]; split-K(16) atomic
__global__ __launch_bounds__(256) void k_embed(
    const float* __restrict__ Y, const float* __restrict__ Et, float* __restrict__ X)
{
    __shared__ __bf16 sm[4][TM * TK];
    mfma_gemm_body<true>(sm[0], sm[1], sm[2], sm[3], Y, 128LL * 8192LL, Et, 8192, nullptr, X, 256,
                         blockIdx.y * TM, blockIdx.x * TN, blockIdx.z * 512, 512);
}

// one-time: Et[256][8192] = E[8192][256]^T
__global__ __launch_bounds__(256) void k_transpose(
    const float* __restrict__ src, float* __restrict__ dst)
{
    __shared__ float t[32][33];
    const int x0 = blockIdx.x * 32;   // along 8192
    const int y0 = blockIdx.y * 32;   // along 256
    const int tx = threadIdx.x & 31, ty = threadIdx.x >> 5;
#pragma unroll
    for (int i = 0; i < 32; i += 8)
        t[ty + i][tx] = src[(long long)(x0 + ty + i) * 256 + (y0 + tx)];
    __syncthreads();
#pragma unroll
    for (int i = 0; i < 32; i += 8)
        dst[(long long)(y0 + ty + i) * 8192 + (x0 + tx)] = t[tx][ty + i];
}

__global__ void k_zero(float* __restrict__ x) {
    x[blockIdx.x * 256 + threadIdx.x] = 0.f;
}

// GRU gate nonlinearity: h = (1-z)*n + z*h
__global__ __launch_bounds__(256) void k_gates(
    const float* __restrict__ gi, const float* __restrict__ gh,
    float* __restrict__ h)
{
    const int idx = blockIdx.x * 256 + threadIdx.x;   // < 128*1024
    const int b = idx >> 10, i = idx & 1023;
    const float* gib = gi + b * 3072;
    const float* ghb = gh + b * 3072;
    const float r = 1.f / (1.f + expf(-(gib[i]        + ghb[i])));
    const float z = 1.f / (1.f + expf(-(gib[i + 1024] + ghb[i + 1024])));
    const float n = tanhf(gib[i + 2048] + r * ghb[i + 2048]);
    h[idx] = (1.f - z) * n + z * h[idx];
}

// ---------------- gumbel + softmax (one block per batch row) ----------------
__device__ __forceinline__ float wred_max(float v) {
#pragma unroll
    for (int off = 32; off > 0; off >>= 1)
        v = fmaxf(v, __shfl_down(v, off, 64));
    return v;
}
__device__ __forceinline__ float wred_sum(float v) {
#pragma unroll
    for (int off = 32; off > 0; off >>= 1)
        v += __shfl_down(v, off, 64);
    return v;
}

__global__ __launch_bounds__(1024) void k_sample(
    const float* __restrict__ logits, const float* __restrict__ temp,
    float* __restrict__ out, float* __restrict__ x, int t)
{
    const int b = blockIdx.x;
    const int tid = threadIdx.x;

    // zero x for next step's embed accumulation
    const int gid = b * 1024 + tid;
    if (gid < 128 * 256) x[gid] = 0.f;

    // key_t = threefry((0,42),(0,t))   [jax fold_in semantics]
    uint32_t k0t, k1t;
    threefry2x32(0u, 42u, 0u, (uint32_t)t, k0t, k1t);

    const float tau = temp[0];
    float s[8];
    float m = -3.4e38f;
#pragma unroll
    for (int j = 0; j < 8; ++j) {
        const int v = tid + j * 1024;
        const float lg = logits[b * 8192 + v];
        const uint32_t idx = (uint32_t)(b * 8192 + v);
        uint32_t o0, o1;
        threefry2x32(k0t, k1t, 0u, idx, o0, o1);
        const uint32_t bits = o0 ^ o1;
        float f = __uint_as_float((bits >> 9) | 0x3f800000u) - 1.0f;
        if (f == 0.0f) f = 1.17549435e-38f;           // uniform minval = tiny
        const float g = -logf(-logf(f));
        s[j] = (lg + g) / tau;
        m = fmaxf(m, s[j]);
    }

    __shared__ float red[16];
    const int lane = tid & 63, wid = tid >> 6;

    float wm = wred_max(m);
    if (lane == 0) red[wid] = wm;
    __syncthreads();
    if (tid < 64) {
        float v = (tid < 16) ? red[tid] : -3.4e38f;
        v = wred_max(v);
        if (tid == 0) red[0] = v;
    }
    __syncthreads();
    m = red[0];
    __syncthreads();

    float e[8];
    float sum = 0.f;
#pragma unroll
    for (int j = 0; j < 8; ++j) {
        e[j] = expf(s[j] - m);
        sum += e[j];
    }
    float ws_ = wred_sum(sum);
    if (lane == 0) red[wid] = ws_;
    __syncthreads();
    if (tid < 64) {
        float v = (tid < 16) ? red[tid] : 0.f;
        v = wred_sum(v);
        if (tid == 0) red[0] = v;
    }
    __syncthreads();
    const float inv = 1.0f / red[0];

    const size_t obase = ((size_t)b * 128 + (size_t)t) * 8192;
#pragma unroll
    for (int j = 0; j < 8; ++j)
        out[obase + tid + j * 1024] = e[j] * inv;
}

// ---------------- launch ----------------
extern "C" void kernel_launch(void* const* d_in, const int* in_sizes, int n_in,
                              void* d_out, int out_size, void* d_ws, size_t ws_size,
                              hipStream_t stream) {
    (void)in_sizes; (void)n_in; (void)out_size; (void)ws_size;
    const float* noise  = (const float*)d_in[0];
    const float* temp   = (const float*)d_in[1];
    const float* W_init = (const float*)d_in[2];
    const float* b_init = (const float*)d_in[3];
    const float* E      = (const float*)d_in[4];
    const float* W_ih   = (const float*)d_in[5];
    const float* W_hh   = (const float*)d_in[6];
    const float* b_ih   = (const float*)d_in[7];
    const float* b_hh   = (const float*)d_in[8];
    const float* W_out  = (const float*)d_in[9];
    const float* b_out  = (const float*)d_in[10];
    float* out = (float*)d_out;

    float* ws     = (float*)d_ws;
    float* h      = ws;                 // 128*1024            = 131072
    float* x      = h  + 131072;        // 128*256             = 32768
    float* gi     = x  + 32768;         // 128*3072            = 393216
    float* gh     = gi + 393216;        // 128*3072            = 393216
    float* logits = gh + 393216;        // 128*8192            = 1048576
    float* Et     = logits + 1048576;   // 256*8192            = 2097152  (E^T, fp32)

    // one-time: Et = E^T
    k_transpose<<<dim3(256, 8), dim3(256), 0, stream>>>(E, Et);
    // x = 0 (x_0 = onehot(pad) @ E = E[0] = 0)
    k_zero<<<dim3(128), dim3(256), 0, stream>>>(x);
    // h0 = noise @ W_init^T + b_init   (M=128,N=1024,K=128)
    k_gemm_abT<<<dim3(1024 / TN, 128 / TM), dim3(256), 0, stream>>>(
        noise, 128LL, W_init, 128LL, b_init, h, 1024, 128);

    for (int t = 0; t < 128; ++t) {
        if (t > 0) {
            // x = y_{t-1} @ E  (rows of d_out at (b, t-1, :), row stride 128*8192)
            k_embed<<<dim3(256 / TN, 128 / TM, 16), dim3(256), 0, stream>>>(
                out + (size_t)(t - 1) * 8192, Et, x);
        }
        k_gru_gemms<<<dim3(3072 / TN, 128 / TM, 2), dim3(256), 0, stream>>>(
            x, h, W_ih, W_hh, b_ih, b_hh, gi, gh);
        k_gates<<<dim3(512), dim3(256), 0, stream>>>(gi, gh, h);
        // logits = h @ W_out^T + b_out  (M=128,N=8192,K=1024)
        k_gemm_abT<<<dim3(8192 / TN, 128 / TM), dim3(256), 0, stream>>>(
            h, 1024LL, W_out, 1024LL, b_out, logits, 8192, 1024);
        // gumbel + softmax -> y_t, also zeroes x for next step
        k_sample<<<dim3(128), dim3(1024), 0, stream>>>(logits, temp, out, x, t);
    }
}

// Round 2
// 7119.321 us; speedup vs baseline: 3.0349x; 1.8834x over previous
//
#include <hip/hip_runtime.h>
#include <stdint.h>

// ---------------- threefry2x32 (bit-exact vs JAX) ----------------
__device__ __forceinline__ uint32_t rotl32(uint32_t v, int r) {
    return (v << r) | (v >> (32 - r));
}

__device__ __forceinline__ void threefry2x32(uint32_t k0, uint32_t k1,
                                             uint32_t x0, uint32_t x1,
                                             uint32_t& o0, uint32_t& o1) {
    const uint32_t k2 = k0 ^ k1 ^ 0x1BD11BDAu;
    x0 += k0; x1 += k1;
#define TF_RND(r) { x0 += x1; x1 = rotl32(x1, r); x1 ^= x0; }
    TF_RND(13) TF_RND(15) TF_RND(26) TF_RND(6)
    x0 += k1; x1 += k2 + 1u;
    TF_RND(17) TF_RND(29) TF_RND(16) TF_RND(24)
    x0 += k2; x1 += k0 + 2u;
    TF_RND(13) TF_RND(15) TF_RND(26) TF_RND(6)
    x0 += k0; x1 += k1 + 3u;
    TF_RND(17) TF_RND(29) TF_RND(16) TF_RND(24)
    x0 += k1; x1 += k2 + 4u;
    TF_RND(13) TF_RND(15) TF_RND(26) TF_RND(6)
    x0 += k2; x1 += k0 + 5u;
#undef TF_RND
    o0 = x0; o1 = x1;
}

// ---------------- MFMA bf16 hi/lo split-precision GEMM ----------------
// C[M,N] = A[M,K] @ B[N,K]^T + bias.  B is PRECONVERTED to bf16 hi/lo planes
// stored tile-major [ntile][ktile][H:4096][L:4096] with the LDS XOR-swizzle
// baked in, so staging is a pure linear async copy (global_load_lds).
// A (activations) is fp32, converted hi/lo at stage time.
// 3-product split: a*b ~= ah*bh + al*bh + ah*bl (rel err ~2^-18).
// Block: 256 thr = 4 waves, tile 64x64, wave 32x32 (2x2 mfma_16x16x32_bf16),
// TK=64, double-buffered LDS, loads for k+1 issued before MFMAs of k.

typedef __attribute__((ext_vector_type(8))) __bf16 bf16x8;
typedef __attribute__((ext_vector_type(4))) __bf16 bf16x4;
typedef __attribute__((ext_vector_type(4))) float f32x4;

__device__ __forceinline__ void async16(const void* g, void* l) {
    __builtin_amdgcn_global_load_lds(
        (const __attribute__((address_space(1))) uint32_t*)g,
        (__attribute__((address_space(3))) uint32_t*)l,
        16, 0, 0);
}

// stage one preconverted 16KB B tile (H+L planes) global -> LDS, async
__device__ __forceinline__ void stageB(const __bf16* src, __bf16* dst, int tid) {
    const int wid = tid >> 6, lane = tid & 63;
    const char* g = (const char*)src + wid * 4096 + lane * 16;
    char* l = (char*)dst + wid * 4096 + lane * 16;
#pragma unroll
    for (int c = 0; c < 4; ++c)
        async16(g + c * 1024, l + c * 1024);
}

__device__ __forceinline__ void loadA(const float* A, long long lda,
                                      int m0, int k0, int tid, float4* ar) {
#pragma unroll
    for (int i = 0; i < 4; ++i) {
        const int flat = i * 256 + tid;
        const int row = flat >> 4, k4 = (flat & 15) << 2;
        ar[i] = *(const float4*)(A + (long long)(m0 + row) * lda + (k0 + k4));
    }
}

__device__ __forceinline__ void cvtWriteA(const float4* ar, __bf16* Hs, int tid) {
#pragma unroll
    for (int i = 0; i < 4; ++i) {
        const int flat = i * 256 + tid;
        const int row = flat >> 4, k4 = (flat & 15) << 2;
        const float4 v = ar[i];
        const __bf16 h0 = (__bf16)v.x, h1 = (__bf16)v.y, h2 = (__bf16)v.z, h3 = (__bf16)v.w;
        const __bf16 l0 = (__bf16)(v.x - (float)h0);
        const __bf16 l1 = (__bf16)(v.y - (float)h1);
        const __bf16 l2 = (__bf16)(v.z - (float)h2);
        const __bf16 l3 = (__bf16)(v.w - (float)h3);
        const int e = (row * 64 + k4) ^ ((row & 7) << 3);
        *(bf16x4*)&Hs[e] = (bf16x4){h0, h1, h2, h3};
        *(bf16x4*)&Hs[4096 + e] = (bf16x4){l0, l1, l2, l3};
    }
}

template<bool ATOMIC>
__device__ __forceinline__ void mfma_gemm_body(
    __bf16* sA, __bf16* sB,                    // sA[2][2][4096], sB[2][2][4096]
    const float* __restrict__ A, long long lda,
    const __bf16* __restrict__ Bp, int ktot,   // planes, K/64 of full B
    const float* __restrict__ bias,
    float* __restrict__ C, int ldc,
    int m0, int n0, int kbase, int ksize)
{
    const int tid  = threadIdx.x;
    const int lane = tid & 63;
    const int wid  = tid >> 6;
    const int wr   = (wid >> 1) << 5;
    const int wc   = (wid & 1) << 5;
    const int fr   = lane & 15;
    const int kg   = lane >> 4;
    const int nt   = ksize >> 6;
    const long long btile0 = (long long)(n0 >> 6) * ktot + (kbase >> 6);

    f32x4 acc[2][2] = {};
    float4 ar[4];

    // prologue: stage tile 0
    stageB(Bp + btile0 * 8192, sB, tid);
    loadA(A, lda, m0, kbase, tid, ar);
    cvtWriteA(ar, sA, tid);
    __syncthreads();   // compiler drains vmcnt(0) -> B tile 0 resident

    for (int t = 0; t < nt; ++t) {
        const int cur = t & 1, nxt = cur ^ 1;
        __bf16* sAc = sA + cur * 8192;
        __bf16* sBc = sB + cur * 8192;
        if (t + 1 < nt) {  // issue next-tile loads BEFORE compute
            stageB(Bp + (btile0 + t + 1) * 8192, sB + nxt * 8192, tid);
            loadA(A, lda, m0, kbase + ((t + 1) << 6), tid, ar);
        }
#pragma unroll
        for (int kc = 0; kc < 2; ++kc) {
            const int kb = kc * 32 + kg * 8;
            bf16x8 ah[2], al[2], bh[2], bl[2];
#pragma unroll
            for (int i = 0; i < 2; ++i) {
                const int r  = wr + i * 16 + fr;
                const int ea = (r * 64 + kb) ^ ((r & 7) << 3);
                ah[i] = *(const bf16x8*)&sAc[ea];
                al[i] = *(const bf16x8*)&sAc[4096 + ea];
                const int cc = wc + i * 16 + fr;
                const int eb = (cc * 64 + kb) ^ ((cc & 7) << 3);
                bh[i] = *(const bf16x8*)&sBc[eb];
                bl[i] = *(const bf16x8*)&sBc[4096 + eb];
            }
#pragma unroll
            for (int i = 0; i < 2; ++i)
#pragma unroll
                for (int j = 0; j < 2; ++j)
                    acc[i][j] = __builtin_amdgcn_mfma_f32_16x16x32_bf16(ah[i], bh[j], acc[i][j], 0, 0, 0);
#pragma unroll
            for (int i = 0; i < 2; ++i)
#pragma unroll
                for (int j = 0; j < 2; ++j)
                    acc[i][j] = __builtin_amdgcn_mfma_f32_16x16x32_bf16(al[i], bh[j], acc[i][j], 0, 0, 0);
#pragma unroll
            for (int i = 0; i < 2; ++i)
#pragma unroll
                for (int j = 0; j < 2; ++j)
                    acc[i][j] = __builtin_amdgcn_mfma_f32_16x16x32_bf16(ah[i], bl[j], acc[i][j], 0, 0, 0);
        }
        if (t + 1 < nt)
            cvtWriteA(ar, sA + nxt * 8192, tid);
        __syncthreads();
    }

    // C/D layout: col = lane&15, row = (lane>>4)*4 + reg
#pragma unroll
    for (int i = 0; i < 2; ++i)
#pragma unroll
        for (int j = 0; j < 2; ++j)
#pragma unroll
            for (int v = 0; v < 4; ++v) {
                const int row = m0 + wr + i * 16 + kg * 4 + v;
                const int col = n0 + wc + j * 16 + fr;
                float val = acc[i][j][v];
                if (ATOMIC) {
                    atomicAdd(&C[(long long)row * ldc + col], val);
                } else {
                    if (bias) val += bias[col];
                    C[(long long)row * ldc + col] = val;
                }
            }
}

#define GEMM_LDS __shared__ __align__(16) __bf16 sA[2 * 8192]; \
                 __shared__ __align__(16) __bf16 sB[2 * 8192];

// h0 = noise @ W_init^T + b_init  (K=128)
__global__ __launch_bounds__(256) void k_h0(
    const float* __restrict__ A, const __bf16* __restrict__ Bp,
    const float* __restrict__ bias, float* __restrict__ C)
{
    GEMM_LDS
    mfma_gemm_body<false>(sA, sB, A, 128, Bp, 2, bias, C, 1024,
                          blockIdx.y * 64, blockIdx.x * 64, 0, 128);
}

// z=0: gi = x@W_ih^T + b_ih (K=256) ; z=1,2: gh halves (K=512 each, no bias)
__global__ __launch_bounds__(256) void k_gru(
    const float* __restrict__ x, const float* __restrict__ h,
    const __bf16* __restrict__ pIH, const __bf16* __restrict__ pHH,
    const float* __restrict__ b_ih,
    float* __restrict__ gi, float* __restrict__ gh0, float* __restrict__ gh1)
{
    GEMM_LDS
    const int z = blockIdx.z;
    if (z == 0)
        mfma_gemm_body<false>(sA, sB, x, 256, pIH, 4, b_ih, gi, 3072,
                              blockIdx.y * 64, blockIdx.x * 64, 0, 256);
    else if (z == 1)
        mfma_gemm_body<false>(sA, sB, h, 1024, pHH, 16, nullptr, gh0, 3072,
                              blockIdx.y * 64, blockIdx.x * 64, 0, 512);
    else
        mfma_gemm_body<false>(sA, sB, h, 1024, pHH, 16, nullptr, gh1, 3072,
                              blockIdx.y * 64, blockIdx.x * 64, 512, 512);
}

// logits split-K=2: lg{0,1} = h @ W_out[:, z*512 : z*512+512]^T  (no bias)
__global__ __launch_bounds__(256) void k_logits(
    const float* __restrict__ h, const __bf16* __restrict__ pWo,
    float* __restrict__ lg0, float* __restrict__ lg1)
{
    GEMM_LDS
    float* C = blockIdx.z ? lg1 : lg0;
    mfma_gemm_body<false>(sA, sB, h, 1024, pWo, 16, nullptr, C, 8192,
                          blockIdx.y * 64, blockIdx.x * 64, blockIdx.z * 512, 512);
}

// x += Y @ E  via preconverted Et planes [4][128] tiles; split-K(16) atomic
__global__ __launch_bounds__(256) void k_embed(
    const float* __restrict__ Y, const __bf16* __restrict__ pEt,
    float* __restrict__ X)
{
    GEMM_LDS
    mfma_gemm_body<true>(sA, sB, Y, 128LL * 8192LL, pEt, 128, nullptr, X, 256,
                         blockIdx.y * 64, blockIdx.x * 64, blockIdx.z * 512, 512);
}

// ---------------- one-time weight preconversion ----------------
// W[N][K] fp32 -> planes tile-major [n/64][k/64][H:4096][L:4096], swizzle baked
__global__ __launch_bounds__(256) void k_prep_wt(
    const float* __restrict__ W, __bf16* __restrict__ P, int K)
{
    const int idx = blockIdx.x * 256 + threadIdx.x;   // one per float4
    const int kq = K >> 2;
    const int n = idx / kq;
    const int k4 = (idx - n * kq) << 2;
    const float4 v = *(const float4*)(W + (long long)n * K + k4);
    const __bf16 h0 = (__bf16)v.x, h1 = (__bf16)v.y, h2 = (__bf16)v.z, h3 = (__bf16)v.w;
    const __bf16 l0 = (__bf16)(v.x - (float)h0);
    const __bf16 l1 = (__bf16)(v.y - (float)h1);
    const __bf16 l2 = (__bf16)(v.z - (float)h2);
    const __bf16 l3 = (__bf16)(v.w - (float)h3);
    const int r = n & 63, c = k4 & 63;
    const long long tbase = ((long long)(n >> 6) * (K >> 6) + (k4 >> 6)) * 8192;
    const int e = (r * 64 + c) ^ ((r & 7) << 3);
    *(bf16x4*)&P[tbase + e] = (bf16x4){h0, h1, h2, h3};
    *(bf16x4*)&P[tbase + 4096 + e] = (bf16x4){l0, l1, l2, l3};
}

// Et planes: B[N=256(d)][K=8192(v)] from E[8192][256]; tiles [4][128]
__global__ __launch_bounds__(256) void k_prep_et(
    const float* __restrict__ E, __bf16* __restrict__ P)
{
    const int idx = blockIdx.x * 256 + threadIdx.x;   // (v4, d)
    const int d = idx & 255;
    const int v4 = (idx >> 8) << 2;
    float x[4];
#pragma unroll
    for (int j = 0; j < 4; ++j)
        x[j] = E[(long long)(v4 + j) * 256 + d];
    __bf16 hh[4], ll[4];
#pragma unroll
    for (int j = 0; j < 4; ++j) {
        hh[j] = (__bf16)x[j];
        ll[j] = (__bf16)(x[j] - (float)hh[j]);
    }
    const int r = d & 63, c = v4 & 63;
    const long long tbase = ((long long)(d >> 6) * 128 + (v4 >> 6)) * 8192;
    const int e = (r * 64 + c) ^ ((r & 7) << 3);
    *(bf16x4*)&P[tbase + e] = (bf16x4){hh[0], hh[1], hh[2], hh[3]};
    *(bf16x4*)&P[tbase + 4096 + e] = (bf16x4){ll[0], ll[1], ll[2], ll[3]};
}

__global__ void k_zero(float* __restrict__ x) {
    x[blockIdx.x * 256 + threadIdx.x] = 0.f;
}

// GRU gates: h = (1-z)*n + z*h ; gh = gh0 + gh1 + b_hh
__global__ __launch_bounds__(256) void k_gates(
    const float* __restrict__ gi,
    const float* __restrict__ gh0, const float* __restrict__ gh1,
    const float* __restrict__ b_hh, float* __restrict__ h)
{
    const int idx = blockIdx.x * 256 + threadIdx.x;   // < 128*1024
    const int b = idx >> 10, i = idx & 1023;
    const float* gib = gi + b * 3072;
    const float* g0 = gh0 + b * 3072;
    const float* g1 = gh1 + b * 3072;
    const float ghr = g0[i]        + g1[i]        + b_hh[i];
    const float ghz = g0[i + 1024] + g1[i + 1024] + b_hh[i + 1024];
    const float ghn = g0[i + 2048] + g1[i + 2048] + b_hh[i + 2048];
    const float r = 1.f / (1.f + expf(-(gib[i]        + ghr)));
    const float z = 1.f / (1.f + expf(-(gib[i + 1024] + ghz)));
    const float n = tanhf(gib[i + 2048] + r * ghn);
    h[idx] = (1.f - z) * n + z * h[idx];
}

// ---------------- gumbel + softmax (one block per batch row) ----------------
__device__ __forceinline__ float wred_max(float v) {
#pragma unroll
    for (int off = 32; off > 0; off >>= 1)
        v = fmaxf(v, __shfl_down(v, off, 64));
    return v;
}
__device__ __forceinline__ float wred_sum(float v) {
#pragma unroll
    for (int off = 32; off > 0; off >>= 1)
        v += __shfl_down(v, off, 64);
    return v;
}

__global__ __launch_bounds__(1024) void k_sample(
    const float* __restrict__ lg0, const float* __restrict__ lg1,
    const float* __restrict__ b_out, const float* __restrict__ temp,
    float* __restrict__ out, float* __restrict__ x, int t)
{
    const int b = blockIdx.x;
    const int tid = threadIdx.x;

    // zero x for next step's embed accumulation
    const int gid = b * 1024 + tid;
    if (gid < 128 * 256) x[gid] = 0.f;

    uint32_t k0t, k1t;
    threefry2x32(0u, 42u, 0u, (uint32_t)t, k0t, k1t);

    const float tau = temp[0];
    float s[8];
    float m = -3.4e38f;
#pragma unroll
    for (int j = 0; j < 8; ++j) {
        const int v = tid + j * 1024;
        const float lg = lg0[b * 8192 + v] + lg1[b * 8192 + v] + b_out[v];
        const uint32_t idx = (uint32_t)(b * 8192 + v);
        uint32_t o0, o1;
        threefry2x32(k0t, k1t, 0u, idx, o0, o1);
        const uint32_t bits = o0 ^ o1;
        float f = __uint_as_float((bits >> 9) | 0x3f800000u) - 1.0f;
        if (f == 0.0f) f = 1.17549435e-38f;           // uniform minval = tiny
        const float g = -logf(-logf(f));
        s[j] = (lg + g) / tau;
        m = fmaxf(m, s[j]);
    }

    __shared__ float red[16];
    const int lane = tid & 63, wid = tid >> 6;

    float wm = wred_max(m);
    if (lane == 0) red[wid] = wm;
    __syncthreads();
    if (tid < 64) {
        float v = (tid < 16) ? red[tid] : -3.4e38f;
        v = wred_max(v);
        if (tid == 0) red[0] = v;
    }
    __syncthreads();
    m = red[0];
    __syncthreads();

    float e[8];
    float sum = 0.f;
#pragma unroll
    for (int j = 0; j < 8; ++j) {
        e[j] = expf(s[j] - m);
        sum += e[j];
    }
    float ws_ = wred_sum(sum);
    if (lane == 0) red[wid] = ws_;
    __syncthreads();
    if (tid < 64) {
        float v = (tid < 16) ? red[tid] : 0.f;
        v = wred_sum(v);
        if (tid == 0) red[0] = v;
    }
    __syncthreads();
    const float inv = 1.0f / red[0];

    const size_t obase = ((size_t)b * 128 + (size_t)t) * 8192;
#pragma unroll
    for (int j = 0; j < 8; ++j)
        out[obase + tid + j * 1024] = e[j] * inv;
}

// ---------------- launch ----------------
extern "C" void kernel_launch(void* const* d_in, const int* in_sizes, int n_in,
                              void* d_out, int out_size, void* d_ws, size_t ws_size,
                              hipStream_t stream) {
    (void)in_sizes; (void)n_in; (void)out_size; (void)ws_size;
    const float* noise  = (const float*)d_in[0];
    const float* temp   = (const float*)d_in[1];
    const float* W_init = (const float*)d_in[2];
    const float* b_init = (const float*)d_in[3];
    const float* E      = (const float*)d_in[4];
    const float* W_ih   = (const float*)d_in[5];
    const float* W_hh   = (const float*)d_in[6];
    const float* b_ih   = (const float*)d_in[7];
    const float* b_hh   = (const float*)d_in[8];
    const float* W_out  = (const float*)d_in[9];
    const float* b_out  = (const float*)d_in[10];
    float* out = (float*)d_out;

    float* ws  = (float*)d_ws;
    float* h   = ws;                    // 128*1024  = 131072
    float* x   = h   + 131072;          // 128*256   = 32768
    float* gi  = x   + 32768;           // 128*3072  = 393216
    float* gh0 = gi  + 393216;          // 128*3072
    float* gh1 = gh0 + 393216;          // 128*3072
    float* lg0 = gh1 + 393216;          // 128*8192  = 1048576
    float* lg1 = lg0 + 1048576;         // 128*8192
    // bf16 hi/lo planes (each source element -> 4 B = 1 float slot)
    __bf16* pWi = (__bf16*)(lg1 + 1048576);          // 1024*128  = 131072 slots
    __bf16* pIH = (__bf16*)((float*)pWi + 131072);   // 3072*256  = 786432
    __bf16* pHH = (__bf16*)((float*)pIH + 786432);   // 3072*1024 = 3145728
    __bf16* pWo = (__bf16*)((float*)pHH + 3145728);  // 8192*1024 = 8388608
    __bf16* pEt = (__bf16*)((float*)pWo + 8388608);  // 256*8192  = 2097152

    // one-time: preconvert weights to swizzled bf16 hi/lo tile planes
    k_prep_wt<<<dim3(1024 * 128 / 4 / 256), dim3(256), 0, stream>>>(W_init, pWi, 128);
    k_prep_wt<<<dim3(3072 * 256 / 4 / 256), dim3(256), 0, stream>>>(W_ih, pIH, 256);
    k_prep_wt<<<dim3(3072 * 1024 / 4 / 256), dim3(256), 0, stream>>>(W_hh, pHH, 1024);
    k_prep_wt<<<dim3(8192 * 1024 / 4 / 256), dim3(256), 0, stream>>>(W_out, pWo, 1024);
    k_prep_et<<<dim3(8192 / 4 * 256 / 256), dim3(256), 0, stream>>>(E, pEt);

    // x = 0 (x_0 = onehot(pad) @ E = E[0] = 0)
    k_zero<<<dim3(128), dim3(256), 0, stream>>>(x);
    // h0 = noise @ W_init^T + b_init
    k_h0<<<dim3(16, 2), dim3(256), 0, stream>>>(noise, pWi, b_init, h);

    for (int t = 0; t < 128; ++t) {
        if (t > 0) {
            // x = y_{t-1} @ E  (rows of out at (b, t-1, :), row stride 128*8192)
            k_embed<<<dim3(4, 2, 16), dim3(256), 0, stream>>>(
                out + (size_t)(t - 1) * 8192, pEt, x);
        }
        k_gru<<<dim3(48, 2, 3), dim3(256), 0, stream>>>(
            x, h, pIH, pHH, b_ih, gi, gh0, gh1);
        k_gates<<<dim3(512), dim3(256), 0, stream>>>(gi, gh0, gh1, b_hh, h);
        // logits halves: lg0/lg1 = h @ W_out^T (split-K=2)
        k_logits<<<dim3(128, 2, 2), dim3(256), 0, stream>>>(h, pWo, lg0, lg1);
        // gumbel + softmax -> y_t (adds lg0+lg1+b_out), zeroes x for next step
        k_sample<<<dim3(128), dim3(1024), 0, stream>>>(lg0, lg1, b_out, temp, out, x, t);
    }
}